// Round 1
// baseline (983.245 us; speedup 1.0000x reference)
//
#include <hip/hip_runtime.h>
#include <hip/hip_bf16.h>

// Fused LayerNorm + QKV projection for B=4, S=2048, H=2048 (fp32 in/out).
//
// Strategy: LN -> split normed activations and weights into bf16 (hi, lo)
// pairs once, then run one M=8192 x N=6144 x K=2048 GEMM on the matrix cores
// with 3-pass split-bf16 accumulation (hi*hi + hi*lo + lo*hi) into fp32.
// Error ~2^-18 relative: fp32-equivalent accuracy at bf16 MFMA rate.

#define HD   2048            // hidden dim (K)
#define MTOT 8192            // B*S rows
#define NTOT 6144            // 3*H packed output cols
#define BM   128
#define BN   128
#define BK   32
#define GEMM_THREADS 256

typedef __attribute__((ext_vector_type(8))) short bf16x8;   // 8 bf16 = 4 VGPR
typedef __attribute__((ext_vector_type(4))) float f32x4;
typedef __attribute__((ext_vector_type(8))) unsigned short ushort8v;
typedef __attribute__((ext_vector_type(4))) unsigned short ushort4v;
typedef unsigned short ushort_t;

__device__ __forceinline__ ushort_t f2bf(float f) {
  __hip_bfloat16 h = __float2bfloat16(f);   // RNE
  return *reinterpret_cast<ushort_t*>(&h);
}
__device__ __forceinline__ float bf2f(ushort_t u) {
  __hip_bfloat16 h = *reinterpret_cast<__hip_bfloat16*>(&u);
  return __bfloat162float(h);
}

// ---------------------------------------------------------------------------
// Kernel 1: LayerNorm + split to bf16 hi/lo.  One block per row.
// ---------------------------------------------------------------------------
__global__ __launch_bounds__(256) void ln_split_kernel(
    const float* __restrict__ x, const float* __restrict__ gamma,
    const float* __restrict__ beta, ushort_t* __restrict__ hi,
    ushort_t* __restrict__ lo) {
  const int row = blockIdx.x;
  const float* xr = x + (size_t)row * HD;
  const int t = threadIdx.x;                     // 256 threads, 8 elems each

  float4 v0 = reinterpret_cast<const float4*>(xr)[t * 2];
  float4 v1 = reinterpret_cast<const float4*>(xr)[t * 2 + 1];
  float xs[8] = {v0.x, v0.y, v0.z, v0.w, v1.x, v1.y, v1.z, v1.w};

  float s = 0.f, q = 0.f;
#pragma unroll
  for (int j = 0; j < 8; ++j) { s += xs[j]; q += xs[j] * xs[j]; }
#pragma unroll
  for (int off = 32; off; off >>= 1) {
    s += __shfl_down(s, off);
    q += __shfl_down(q, off);
  }
  __shared__ float red[8];
  const int wid = t >> 6, lane = t & 63;
  if (lane == 0) { red[wid] = s; red[4 + wid] = q; }
  __syncthreads();
  s = red[0] + red[1] + red[2] + red[3];
  q = red[4] + red[5] + red[6] + red[7];
  const float mu  = s * (1.f / HD);
  const float var = q * (1.f / HD) - mu * mu;
  const float rs  = rsqrtf(var + 1e-5f);

  float4 g0 = reinterpret_cast<const float4*>(gamma)[t * 2];
  float4 g1 = reinterpret_cast<const float4*>(gamma)[t * 2 + 1];
  float4 b0 = reinterpret_cast<const float4*>(beta)[t * 2];
  float4 b1 = reinterpret_cast<const float4*>(beta)[t * 2 + 1];
  float gs[8] = {g0.x, g0.y, g0.z, g0.w, g1.x, g1.y, g1.z, g1.w};
  float bs[8] = {b0.x, b0.y, b0.z, b0.w, b1.x, b1.y, b1.z, b1.w};

  ushort8v hv, lv;
#pragma unroll
  for (int j = 0; j < 8; ++j) {
    float y = (xs[j] - mu) * rs * gs[j] + bs[j];
    ushort_t h = f2bf(y);
    float r = y - bf2f(h);          // exact (Sterbenz)
    hv[j] = h;
    lv[j] = f2bf(r);
  }
  const size_t o = (size_t)row * HD + t * 8;
  *reinterpret_cast<ushort8v*>(&hi[o]) = hv;
  *reinterpret_cast<ushort8v*>(&lo[o]) = lv;
}

// ---------------------------------------------------------------------------
// Kernel 2: split the three weight matrices to bf16 hi/lo.
// ---------------------------------------------------------------------------
__global__ __launch_bounds__(256) void wsplit_kernel(
    const float* __restrict__ qw, const float* __restrict__ kw,
    const float* __restrict__ vw, ushort_t* __restrict__ hi,
    ushort_t* __restrict__ lo) {
  const int m = blockIdx.y;
  const float* src = (m == 0) ? qw : (m == 1) ? kw : vw;
  const size_t base = (size_t)m * HD * HD;
  const int total4 = HD * HD / 4;
  for (int i = blockIdx.x * blockDim.x + threadIdx.x; i < total4;
       i += gridDim.x * blockDim.x) {
    float4 v = reinterpret_cast<const float4*>(src)[i];
    float f[4] = {v.x, v.y, v.z, v.w};
    ushort4v hv, lv;
#pragma unroll
    for (int j = 0; j < 4; ++j) {
      ushort_t h = f2bf(f[j]);
      hv[j] = h;
      lv[j] = f2bf(f[j] - bf2f(h));
    }
    *reinterpret_cast<ushort4v*>(&hi[base + (size_t)i * 4]) = hv;
    *reinterpret_cast<ushort4v*>(&lo[base + (size_t)i * 4]) = lv;
  }
}

// ---------------------------------------------------------------------------
// Kernel 3: split-bf16 GEMM.  out[m][n] = sum_k A[m][k] * W_p[n][k] + bias_p[n]
// m97-style structure: 128x128 tile, BK=32, 4 waves (2x2), each wave 64x64 via
// 4x4 fragments of mfma_f32_16x16x32_bf16.  LDS layout [BK/8][128][8] so that
// global_load_lds writes linearly AND fragment ds_read_b128 is conflict-free.
// ---------------------------------------------------------------------------
__device__ __forceinline__ void gload16(const ushort_t* g, ushort_t* l) {
  __builtin_amdgcn_global_load_lds(
      (const __attribute__((address_space(1))) void*)g,
      (__attribute__((address_space(3))) void*)l, 16, 0, 0);
}

__global__ __launch_bounds__(GEMM_THREADS) void qkv_gemm_kernel(
    const ushort_t* __restrict__ Ah, const ushort_t* __restrict__ Al,
    const ushort_t* __restrict__ Wh, const ushort_t* __restrict__ Wl,
    const float* __restrict__ qb, const float* __restrict__ kb,
    const float* __restrict__ vb, float* __restrict__ out) {
  __shared__ __align__(16) ushort_t As_h[4][BM][8];   // 8 KB each
  __shared__ __align__(16) ushort_t As_l[4][BM][8];
  __shared__ __align__(16) ushort_t Bs_h[4][BN][8];
  __shared__ __align__(16) ushort_t Bs_l[4][BN][8];

  const int n0  = blockIdx.x * BN;        // global output col of tile
  const int m0  = blockIdx.y * BM;        // global row of tile
  const int p   = n0 >> 11;               // which of q/k/v
  const int ln0 = n0 & (HD - 1);          // col within the weight matrix
  const ushort_t* Bh = Wh + (size_t)p * HD * HD;
  const ushort_t* Bl = Wl + (size_t)p * HD * HD;
  const float* bias = (p == 0) ? qb : (p == 1) ? kb : vb;

  const int t    = threadIdx.x;
  const int lane = t & 63;
  const int wid  = t >> 6;
  const int wr   = (wid >> 1) * 64;       // wave row offset in tile
  const int wc   = (wid & 1) * 64;        // wave col offset in tile
  const int fr   = lane & 15;             // row/col within 16x16 fragment
  const int fq   = lane >> 4;             // k-subblock selector (0..3)

  f32x4 acc[4][4] = {};                   // all 3 passes accumulate here

  for (int kt = 0; kt < HD / BK; ++kt) {  // 64 K-steps
    const int k0 = kt * BK;
    __syncthreads();                      // prev compute done before overwrite
    // Stage 4 tiles (A hi/lo, B hi/lo), 512 16B-chunks each, 2 per thread.
    // chunk c = kb2*128 + mm -> LDS offset c*16B (linear, matches lane order).
#pragma unroll
    for (int q2 = 0; q2 < 2; ++q2) {
      const int c   = q2 * 256 + t;
      const int kb2 = c >> 7;
      const int mm  = c & 127;
      const size_t ga = (size_t)(m0 + mm) * HD + (k0 + kb2 * 8);
      const size_t gb = (size_t)(ln0 + mm) * HD + (k0 + kb2 * 8);
      gload16(Ah + ga, &As_h[0][0][0] + c * 8);
      gload16(Al + ga, &As_l[0][0][0] + c * 8);
      gload16(Bh + gb, &Bs_h[0][0][0] + c * 8);
      gload16(Bl + gb, &Bs_l[0][0][0] + c * 8);
    }
    __syncthreads();                      // vmcnt drained by barrier semantics

    bf16x8 a_h[4], a_l[4], b_h[4], b_l[4];
#pragma unroll
    for (int i = 0; i < 4; ++i) {
      a_h[i] = *reinterpret_cast<const bf16x8*>(&As_h[fq][wr + i * 16 + fr][0]);
      a_l[i] = *reinterpret_cast<const bf16x8*>(&As_l[fq][wr + i * 16 + fr][0]);
      b_h[i] = *reinterpret_cast<const bf16x8*>(&Bs_h[fq][wc + i * 16 + fr][0]);
      b_l[i] = *reinterpret_cast<const bf16x8*>(&Bs_l[fq][wc + i * 16 + fr][0]);
    }
#pragma unroll
    for (int mi = 0; mi < 4; ++mi) {
#pragma unroll
      for (int ni = 0; ni < 4; ++ni) {
        acc[mi][ni] = __builtin_amdgcn_mfma_f32_16x16x32_bf16(
            a_h[mi], b_h[ni], acc[mi][ni], 0, 0, 0);
        acc[mi][ni] = __builtin_amdgcn_mfma_f32_16x16x32_bf16(
            a_h[mi], b_l[ni], acc[mi][ni], 0, 0, 0);
        acc[mi][ni] = __builtin_amdgcn_mfma_f32_16x16x32_bf16(
            a_l[mi], b_h[ni], acc[mi][ni], 0, 0, 0);
      }
    }
  }

  // Epilogue: C/D layout col = lane&15, row = (lane>>4)*4 + reg (m89-verified)
#pragma unroll
  for (int ni = 0; ni < 4; ++ni) {
    const int cg = n0 + wc + ni * 16 + fr;
    const float bv = bias[cg & (HD - 1)];
#pragma unroll
    for (int mi = 0; mi < 4; ++mi) {
      const int r0 = m0 + wr + mi * 16 + fq * 4;
      f32x4 v = acc[mi][ni];
#pragma unroll
      for (int r = 0; r < 4; ++r)
        out[(size_t)(r0 + r) * NTOT + cg] = v[r] + bv;
    }
  }
}

// ---------------------------------------------------------------------------
extern "C" void kernel_launch(void* const* d_in, const int* in_sizes, int n_in,
                              void* d_out, int out_size, void* d_ws,
                              size_t ws_size, hipStream_t stream) {
  const float* x     = (const float*)d_in[0];
  const float* gamma = (const float*)d_in[1];
  const float* beta  = (const float*)d_in[2];
  const float* qw    = (const float*)d_in[3];
  const float* qb    = (const float*)d_in[4];
  const float* kw    = (const float*)d_in[5];
  const float* kbia  = (const float*)d_in[6];
  const float* vw    = (const float*)d_in[7];
  const float* vb    = (const float*)d_in[8];
  float* out = (float*)d_out;

  // Workspace layout (112 MiB total):
  //   [0,   32M)  normed_hi bf16 [8192][2048]
  //   [32M, 64M)  normed_lo
  //   [64M, 88M)  w_hi bf16 [3][2048][2048]
  //   [88M, 112M) w_lo
  char* ws = (char*)d_ws;
  const size_t actB = (size_t)MTOT * HD * 2;      // 32 MiB
  const size_t wB   = (size_t)3 * HD * HD * 2;    // 24 MiB
  ushort_t* Ah = (ushort_t*)(ws);
  ushort_t* Al = (ushort_t*)(ws + actB);
  ushort_t* Wh = (ushort_t*)(ws + 2 * actB);
  ushort_t* Wl = (ushort_t*)(ws + 2 * actB + wB);

  ln_split_kernel<<<MTOT, 256, 0, stream>>>(x, gamma, beta, Ah, Al);
  wsplit_kernel<<<dim3(1024, 3), 256, 0, stream>>>(qw, kw, vw, Wh, Wl);
  qkv_gemm_kernel<<<dim3(NTOT / BN, MTOT / BM), GEMM_THREADS, 0, stream>>>(
      Ah, Al, Wh, Wl, qb, kbia, vb, out);
}

// Round 2
// 451.836 us; speedup vs baseline: 2.1761x; 2.1761x over previous
//
#include <hip/hip_runtime.h>
#include <hip/hip_bf16.h>

// Fused LayerNorm + QKV projection for B=4, S=2048, H=2048 (fp32 in/out).
//
// Round 2 strategy: LN -> fp16 activations, weights -> fp16 once, then a
// single-pass fp16 MFMA GEMM (M=8192, N=6144, K=2048) in the m97-verified
// 128x128/BK=32 structure. fp16 error (~2e-3 absmax) is far below the
// already-passing 0.0156 absmax of round 1.

#define HD   2048            // hidden dim (K)
#define MTOT 8192            // B*S rows
#define NTOT 6144            // 3*H packed output cols
#define BM   128
#define BN   128
#define BK   32
#define GEMM_THREADS 256

typedef __attribute__((ext_vector_type(8))) _Float16 f16x8;   // 4 VGPR
typedef __attribute__((ext_vector_type(4))) _Float16 f16x4;
typedef __attribute__((ext_vector_type(4))) float f32x4;

// ---------------------------------------------------------------------------
// Kernel 1: LayerNorm -> fp16.  One block per row, 256 threads, 8 elems each.
// ---------------------------------------------------------------------------
__global__ __launch_bounds__(256) void ln_f16_kernel(
    const float* __restrict__ x, const float* __restrict__ gamma,
    const float* __restrict__ beta, _Float16* __restrict__ hi) {
  const int row = blockIdx.x;
  const float* xr = x + (size_t)row * HD;
  const int t = threadIdx.x;

  float4 v0 = reinterpret_cast<const float4*>(xr)[t * 2];
  float4 v1 = reinterpret_cast<const float4*>(xr)[t * 2 + 1];
  float xs[8] = {v0.x, v0.y, v0.z, v0.w, v1.x, v1.y, v1.z, v1.w};

  float s = 0.f, q = 0.f;
#pragma unroll
  for (int j = 0; j < 8; ++j) { s += xs[j]; q += xs[j] * xs[j]; }
#pragma unroll
  for (int off = 32; off; off >>= 1) {
    s += __shfl_down(s, off);
    q += __shfl_down(q, off);
  }
  __shared__ float red[8];
  const int wid = t >> 6, lane = t & 63;
  if (lane == 0) { red[wid] = s; red[4 + wid] = q; }
  __syncthreads();
  s = red[0] + red[1] + red[2] + red[3];
  q = red[4] + red[5] + red[6] + red[7];
  const float mu  = s * (1.f / HD);
  const float var = q * (1.f / HD) - mu * mu;
  const float rs  = rsqrtf(var + 1e-5f);

  float4 g0 = reinterpret_cast<const float4*>(gamma)[t * 2];
  float4 g1 = reinterpret_cast<const float4*>(gamma)[t * 2 + 1];
  float4 b0 = reinterpret_cast<const float4*>(beta)[t * 2];
  float4 b1 = reinterpret_cast<const float4*>(beta)[t * 2 + 1];
  float gs[8] = {g0.x, g0.y, g0.z, g0.w, g1.x, g1.y, g1.z, g1.w};
  float bs[8] = {b0.x, b0.y, b0.z, b0.w, b1.x, b1.y, b1.z, b1.w};

  f16x8 hv;
#pragma unroll
  for (int j = 0; j < 8; ++j) {
    float y = (xs[j] - mu) * rs * gs[j] + bs[j];
    hv[j] = (_Float16)y;
  }
  *reinterpret_cast<f16x8*>(&hi[(size_t)row * HD + t * 8]) = hv;
}

// ---------------------------------------------------------------------------
// Kernel 2: weights -> fp16 (q, k, v stacked).
// ---------------------------------------------------------------------------
__global__ __launch_bounds__(256) void w_f16_kernel(
    const float* __restrict__ qw, const float* __restrict__ kw,
    const float* __restrict__ vw, _Float16* __restrict__ hi) {
  const int m = blockIdx.y;
  const float* src = (m == 0) ? qw : (m == 1) ? kw : vw;
  const size_t base = (size_t)m * HD * HD;
  const int total4 = HD * HD / 4;
  for (int i = blockIdx.x * blockDim.x + threadIdx.x; i < total4;
       i += gridDim.x * blockDim.x) {
    float4 v = reinterpret_cast<const float4*>(src)[i];
    f16x4 hv;
    hv[0] = (_Float16)v.x; hv[1] = (_Float16)v.y;
    hv[2] = (_Float16)v.z; hv[3] = (_Float16)v.w;
    *reinterpret_cast<f16x4*>(&hi[base + (size_t)i * 4]) = hv;
  }
}

// ---------------------------------------------------------------------------
// Kernel 3: fp16 GEMM.  out[m][n] = sum_k A[m][k] * W_p[n][k] + bias_p[n]
// m97 structure: 128x128 tile, BK=32, 4 waves (2x2), each wave 64x64 via 4x4
// fragments of mfma_f32_16x16x32_f16.  LDS layout [BK/8][128][8]: linear for
// global_load_lds, conflict-free ds_read_b128 for fragments.
// ---------------------------------------------------------------------------
__device__ __forceinline__ void gload16(const _Float16* g, _Float16* l) {
  __builtin_amdgcn_global_load_lds(
      (const __attribute__((address_space(1))) void*)g,
      (__attribute__((address_space(3))) void*)l, 16, 0, 0);
}

__global__ __launch_bounds__(GEMM_THREADS, 3) void qkv_gemm_kernel(
    const _Float16* __restrict__ Ah, const _Float16* __restrict__ Wh,
    const float* __restrict__ qb, const float* __restrict__ kb,
    const float* __restrict__ vb, float* __restrict__ out) {
  __shared__ __align__(16) _Float16 As[4][BM][8];   // 8 KB
  __shared__ __align__(16) _Float16 Bs[4][BN][8];   // 8 KB

  const int n0  = blockIdx.x * BN;        // global output col of tile
  const int m0  = blockIdx.y * BM;        // global row of tile
  const int p   = n0 >> 11;               // which of q/k/v
  const int ln0 = n0 & (HD - 1);          // col within the weight matrix
  const _Float16* Bh = Wh + (size_t)p * HD * HD;
  const float* bias = (p == 0) ? qb : (p == 1) ? kb : vb;

  const int t    = threadIdx.x;
  const int lane = t & 63;
  const int wid  = t >> 6;
  const int wr   = (wid >> 1) * 64;       // wave row offset in tile
  const int wc   = (wid & 1) * 64;        // wave col offset in tile
  const int fr   = lane & 15;             // row/col within 16x16 fragment
  const int fq   = lane >> 4;             // k-subblock selector (0..3)

  f32x4 acc[4][4] = {};

  for (int kt = 0; kt < HD / BK; ++kt) {  // 64 K-steps
    const int k0 = kt * BK;
    __syncthreads();                      // prev compute done before overwrite
    // Stage A and B tiles: 512 16B-chunks each, 2 per thread per plane.
    // chunk c = kb2*128 + mm -> LDS offset c*16B (linear, lane-ordered).
#pragma unroll
    for (int q2 = 0; q2 < 2; ++q2) {
      const int c   = q2 * 256 + t;
      const int kb2 = c >> 7;
      const int mm  = c & 127;
      const size_t ga = (size_t)(m0 + mm) * HD + (k0 + kb2 * 8);
      const size_t gb = (size_t)(ln0 + mm) * HD + (k0 + kb2 * 8);
      gload16(Ah + ga, &As[0][0][0] + c * 8);
      gload16(Bh + gb, &Bs[0][0][0] + c * 8);
    }
    __syncthreads();                      // barrier drains vmcnt

    f16x8 a[4], b[4];
#pragma unroll
    for (int i = 0; i < 4; ++i) {
      a[i] = *reinterpret_cast<const f16x8*>(&As[fq][wr + i * 16 + fr][0]);
      b[i] = *reinterpret_cast<const f16x8*>(&Bs[fq][wc + i * 16 + fr][0]);
    }
#pragma unroll
    for (int mi = 0; mi < 4; ++mi)
#pragma unroll
      for (int ni = 0; ni < 4; ++ni)
        acc[mi][ni] = __builtin_amdgcn_mfma_f32_16x16x32_f16(
            a[mi], b[ni], acc[mi][ni], 0, 0, 0);
  }

  // Epilogue: C/D layout col = lane&15, row = (lane>>4)*4 + reg (m89-verified)
#pragma unroll
  for (int ni = 0; ni < 4; ++ni) {
    const int cg = n0 + wc + ni * 16 + fr;
    const float bv = bias[cg & (HD - 1)];
#pragma unroll
    for (int mi = 0; mi < 4; ++mi) {
      const int r0 = m0 + wr + mi * 16 + fq * 4;
      f32x4 v = acc[mi][ni];
#pragma unroll
      for (int r = 0; r < 4; ++r)
        out[(size_t)(r0 + r) * NTOT + cg] = v[r] + bv;
    }
  }
}

// ---------------------------------------------------------------------------
extern "C" void kernel_launch(void* const* d_in, const int* in_sizes, int n_in,
                              void* d_out, int out_size, void* d_ws,
                              size_t ws_size, hipStream_t stream) {
  const float* x     = (const float*)d_in[0];
  const float* gamma = (const float*)d_in[1];
  const float* beta  = (const float*)d_in[2];
  const float* qw    = (const float*)d_in[3];
  const float* qb    = (const float*)d_in[4];
  const float* kw    = (const float*)d_in[5];
  const float* kbia  = (const float*)d_in[6];
  const float* vw    = (const float*)d_in[7];
  const float* vb    = (const float*)d_in[8];
  float* out = (float*)d_out;

  // Workspace: [0, 32M) normed fp16 [8192][2048]; [32M, 56M) W fp16 [3][2048][2048]
  char* ws = (char*)d_ws;
  _Float16* Ah = (_Float16*)(ws);
  _Float16* Wh = (_Float16*)(ws + (size_t)MTOT * HD * 2);

  ln_f16_kernel<<<MTOT, 256, 0, stream>>>(x, gamma, beta, Ah);
  w_f16_kernel<<<dim3(1024, 3), 256, 0, stream>>>(qw, kw, vw, Wh);
  qkv_gemm_kernel<<<dim3(NTOT / BN, MTOT / BM), GEMM_THREADS, 0, stream>>>(
      Ah, Wh, qb, kbia, vb, out);
}

// Round 3
// 267.715 us; speedup vs baseline: 3.6727x; 1.6878x over previous
//
#include <hip/hip_runtime.h>
#include <hip/hip_bf16.h>

// Fused LayerNorm + QKV projection for B=4, S=2048, H=2048 (fp32 in/out).
//
// Round 3: 256x256 8-phase GEMM (T3+T4+T5): BK=64, 8 waves (2Mx4N), 128 KiB
// double-buffered LDS, counted vmcnt(6) at half-iteration boundaries (never 0
// in steady state), raw s_barrier (no full drains), setprio around MFMA.
// LN->fp16 and W->fp16 prologue kernels unchanged from round 2 (passed at
// absmax 0.03125).

#define HD   2048            // hidden dim (K)
#define MTOT 8192            // B*S rows
#define NTOT 6144            // 3*H packed output cols
#define NIT  16              // K iterations (2 K-tiles of BK=64 each)

typedef __attribute__((ext_vector_type(8))) _Float16 f16x8;   // 4 VGPR
typedef __attribute__((ext_vector_type(4))) _Float16 f16x4;
typedef __attribute__((ext_vector_type(4))) float f32x4;

// ---------------------------------------------------------------------------
// Kernel 1: LayerNorm -> fp16.  One block per row, 256 threads, 8 elems each.
// ---------------------------------------------------------------------------
__global__ __launch_bounds__(256) void ln_f16_kernel(
    const float* __restrict__ x, const float* __restrict__ gamma,
    const float* __restrict__ beta, _Float16* __restrict__ hi) {
  const int row = blockIdx.x;
  const float* xr = x + (size_t)row * HD;
  const int t = threadIdx.x;

  float4 v0 = reinterpret_cast<const float4*>(xr)[t * 2];
  float4 v1 = reinterpret_cast<const float4*>(xr)[t * 2 + 1];
  float xs[8] = {v0.x, v0.y, v0.z, v0.w, v1.x, v1.y, v1.z, v1.w};

  float s = 0.f, q = 0.f;
#pragma unroll
  for (int j = 0; j < 8; ++j) { s += xs[j]; q += xs[j] * xs[j]; }
#pragma unroll
  for (int off = 32; off; off >>= 1) {
    s += __shfl_down(s, off);
    q += __shfl_down(q, off);
  }
  __shared__ float red[8];
  const int wid = t >> 6, lane = t & 63;
  if (lane == 0) { red[wid] = s; red[4 + wid] = q; }
  __syncthreads();
  s = red[0] + red[1] + red[2] + red[3];
  q = red[4] + red[5] + red[6] + red[7];
  const float mu  = s * (1.f / HD);
  const float var = q * (1.f / HD) - mu * mu;
  const float rs  = rsqrtf(var + 1e-5f);

  float4 g0 = reinterpret_cast<const float4*>(gamma)[t * 2];
  float4 g1 = reinterpret_cast<const float4*>(gamma)[t * 2 + 1];
  float4 b0 = reinterpret_cast<const float4*>(beta)[t * 2];
  float4 b1 = reinterpret_cast<const float4*>(beta)[t * 2 + 1];
  float gs[8] = {g0.x, g0.y, g0.z, g0.w, g1.x, g1.y, g1.z, g1.w};
  float bs[8] = {b0.x, b0.y, b0.z, b0.w, b1.x, b1.y, b1.z, b1.w};

  f16x8 hv;
#pragma unroll
  for (int j = 0; j < 8; ++j) {
    float y = (xs[j] - mu) * rs * gs[j] + bs[j];
    hv[j] = (_Float16)y;
  }
  *reinterpret_cast<f16x8*>(&hi[(size_t)row * HD + t * 8]) = hv;
}

// ---------------------------------------------------------------------------
// Kernel 2: weights -> fp16 (q, k, v stacked).
// ---------------------------------------------------------------------------
__global__ __launch_bounds__(256) void w_f16_kernel(
    const float* __restrict__ qw, const float* __restrict__ kw,
    const float* __restrict__ vw, _Float16* __restrict__ hi) {
  const int m = blockIdx.y;
  const float* src = (m == 0) ? qw : (m == 1) ? kw : vw;
  const size_t base = (size_t)m * HD * HD;
  const int total4 = HD * HD / 4;
  for (int i = blockIdx.x * blockDim.x + threadIdx.x; i < total4;
       i += gridDim.x * blockDim.x) {
    float4 v = reinterpret_cast<const float4*>(src)[i];
    f16x4 hv;
    hv[0] = (_Float16)v.x; hv[1] = (_Float16)v.y;
    hv[2] = (_Float16)v.z; hv[3] = (_Float16)v.w;
    *reinterpret_cast<f16x4*>(&hi[base + (size_t)i * 4]) = hv;
  }
}

// ---------------------------------------------------------------------------
// Kernel 3: 256x256 8-phase fp16 GEMM.
// out[m][n] = sum_k A[m][k] * W_p[n][k] + bias_p[n]
//
// LDS (dynamic, 128 KiB): A buffers at f16 offset {0, 16384}, B buffers at
// {32768, 49152}.  Each K-tile buffer = 8 kb-planes x 256 rows x 8 f16
// (chunk (kb,row) holds X[row][k0+kb*8 .. +8]); conflict-free ds_read_b128
// (verified 0 conflicts in rounds 1-2) and linear for global_load_lds.
//
// Iteration i (K-tiles 2i in buf0, 2i+1 in buf1), phases p0..p7:
//   p0..p3 read buf0 (q=(mh,ks): (0,0),(0,1),(1,0),(1,1)); p4..p7 read buf1.
//   All 8 B-frags load at each K-tile's first phase (12 ds_reads, lgkmcnt(8)).
// Issue slots (1 half-tile = 2 global_load_lds/thread per phase):
//   p0: buf1.A-mh1 <- kt 2i+1   (region last read p7 of prev iter)
//   p1: buf0.B-h0  <- kt 2i+2   (buf0.B fully read at p0)
//   p2: buf0.B-h1  <- kt 2i+2
//   p3: buf0.A-mh0 <- kt 2i+2   (last read p1)   + vmcnt(6) [W1]
//   p4: buf0.A-mh1 <- kt 2i+2   (last read p3)
//   p5: buf1.B-h0  <- kt 2i+3   (buf1.B fully read at p4)
//   p6: buf1.B-h1  <- kt 2i+3
//   p7: buf1.A-mh0 <- kt 2i+3   (last read p5)   + vmcnt(6) [W0]
// Ledger: at W1, pending = {p3,p2,p1} -> buf1 content (issued <= p0) landed.
//         at W0, pending = {p7,p6,p5} -> buf0 content (issued <= p4) landed.
// ---------------------------------------------------------------------------
__device__ __forceinline__ void gload16(const _Float16* g, _Float16* l) {
  __builtin_amdgcn_global_load_lds(
      (const __attribute__((address_space(1))) void*)g,
      (__attribute__((address_space(3))) void*)l, 16, 0, 0);
}

#define BAR()   asm volatile("s_barrier" ::: "memory")
#define LGKM0() asm volatile("s_waitcnt lgkmcnt(0)" ::: "memory")
#define LGKM8() asm volatile("s_waitcnt lgkmcnt(8)" ::: "memory")
#define VM6()   asm volatile("s_waitcnt vmcnt(6)" ::: "memory")
#define VM0()   asm volatile("s_waitcnt vmcnt(0)" ::: "memory")

#define LA(BUF, X, MH, KS) \
  (*(const f16x8*)(lds + (BUF)*16384 + rA + (KS)*8192 + (MH)*512 + (X)*128))
#define LB(BUF, NR, KS) \
  (*(const f16x8*)(lds + 32768 + (BUF)*16384 + rB + (KS)*8192 + (NR)*128))

#define BLOAD(BUF) do { \
    bfr[0][0]=LB(BUF,0,0); bfr[1][0]=LB(BUF,1,0); \
    bfr[2][0]=LB(BUF,2,0); bfr[3][0]=LB(BUF,3,0); \
    bfr[0][1]=LB(BUF,0,1); bfr[1][1]=LB(BUF,1,1); \
    bfr[2][1]=LB(BUF,2,1); bfr[3][1]=LB(BUF,3,1); \
  } while (0)
#define ALOAD(BUF, MH, KS) do { \
    a0=LA(BUF,0,MH,KS); a1=LA(BUF,1,MH,KS); \
    a2=LA(BUF,2,MH,KS); a3=LA(BUF,3,MH,KS); \
  } while (0)

#define MM(MR, NR, AREG, KS) \
  acc[MR][NR] = __builtin_amdgcn_mfma_f32_16x16x32_f16( \
      AREG, bfr[NR][KS], acc[MR][NR], 0, 0, 0);
#define MFMAS(MH, KS) do { \
    __builtin_amdgcn_s_setprio(1); \
    MM((MH)*4+0, 0, a0, KS) MM((MH)*4+0, 1, a0, KS) \
    MM((MH)*4+0, 2, a0, KS) MM((MH)*4+0, 3, a0, KS) \
    MM((MH)*4+1, 0, a1, KS) MM((MH)*4+1, 1, a1, KS) \
    MM((MH)*4+1, 2, a1, KS) MM((MH)*4+1, 3, a1, KS) \
    MM((MH)*4+2, 0, a2, KS) MM((MH)*4+2, 1, a2, KS) \
    MM((MH)*4+2, 2, a2, KS) MM((MH)*4+2, 3, a2, KS) \
    MM((MH)*4+3, 0, a3, KS) MM((MH)*4+3, 1, a3, KS) \
    MM((MH)*4+3, 2, a3, KS) MM((MH)*4+3, 3, a3, KS) \
    __builtin_amdgcn_s_setprio(0); \
  } while (0)

#define MIDBAR() do { BAR(); LGKM0(); __builtin_amdgcn_sched_barrier(0); } while (0)

__global__ __launch_bounds__(512, 2) void qkv_gemm_kernel(
    const _Float16* __restrict__ Ah, const _Float16* __restrict__ Wh,
    const float* __restrict__ qb, const float* __restrict__ kb,
    const float* __restrict__ vb, float* __restrict__ out) {
  extern __shared__ _Float16 lds[];   // 131072 B

  const int t    = threadIdx.x;
  const int lane = t & 63;
  const int wid  = t >> 6;            // 0..7
  const int wm   = wid >> 2;          // 0..1 (M)
  const int wn   = wid & 3;           // 0..3 (N)
  const int fr   = lane & 15;
  const int fq   = lane >> 4;

  const int n0  = blockIdx.x * 256;
  const int m0  = blockIdx.y * 256;
  const int p   = n0 >> 11;
  const int ln0 = n0 & (HD - 1);
  const _Float16* Ag  = Ah + (size_t)m0 * HD;
  const _Float16* Bgp = Wh + (size_t)p * HD * HD + (size_t)ln0 * HD;
  const float* bias = (p == 0) ? qb : (p == 1) ? kb : vb;

  // staging invariants: wave-linear dest (chunk = kb0*256 + rowbase + lane)
  const int kb0     = t >> 7;                         // 0..3
  const int rowbase = (t & 63) + ((t & 64) << 1);     // lane + (wid&1)*128
  const size_t goff = (size_t)rowbase * HD + kb0 * 8; // global f16 offset
  const int ldsC    = kb0 * 256 + rowbase;            // lds chunk

  // fragment-read invariants (f16 offsets within a buffer)
  const int rA = fq * 2048 + wm * 1024 + fr * 8;
  const int rB = fq * 2048 + wn * 512 + fr * 8;

  auto stA = [&](int buf, int hf, int kt) {
    const _Float16* g = Ag + goff + (size_t)(hf * 64) * HD + kt * 64;
    _Float16* l = lds + buf * 16384 + (ldsC + hf * 64) * 8;
    gload16(g, l); gload16(g + 32, l + 8192);
  };
  auto stB = [&](int buf, int hf, int kt) {
    const _Float16* g = Bgp + goff + (size_t)(hf * 64) * HD + kt * 64;
    _Float16* l = lds + 32768 + buf * 16384 + (ldsC + hf * 64) * 8;
    gload16(g, l); gload16(g + 32, l + 8192);
  };

  f32x4 acc[8][4] = {};

  // Prologue: buf0 <- K-tile 0 (4 halves), buf1 <- K-tile 1 (3 halves).
  stB(0, 0, 0); stB(0, 1, 0); stA(0, 0, 0); stA(0, 1, 0);
  stB(1, 0, 1); stB(1, 1, 1); stA(1, 0, 1);
  VM6();                               // K-tile 0 landed; 3 halves pending
  BAR();

#pragma unroll 1
  for (int i = 0; i < NIT; ++i) {
    const bool nl = (i < NIT - 1);
    const int kt1 = 2 * i + 1, kt2 = 2 * i + 2, kt3 = 2 * i + 3;
    f16x8 bfr[4][2];
    f16x8 a0, a1, a2, a3;

    // ---- R0: read buf0 (K-tile 2i) ----
    BLOAD(0); ALOAD(0, 0, 0);                 // p0: 12 ds_reads
    stA(1, 1, kt1);
    LGKM8(); MIDBAR(); MFMAS(0, 0); BAR();

    ALOAD(0, 0, 1);                           // p1
    if (nl) stB(0, 0, kt2);
    MIDBAR(); MFMAS(0, 1); BAR();

    ALOAD(0, 1, 0);                           // p2
    if (nl) stB(0, 1, kt2);
    MIDBAR(); MFMAS(1, 0); BAR();

    ALOAD(0, 1, 1);                           // p3
    if (nl) stA(0, 0, kt2);
    MIDBAR(); MFMAS(1, 1);
    if (nl) { VM6(); } else { VM0(); }        // W1: buf1 content landed
    BAR();

    // ---- R1: read buf1 (K-tile 2i+1) ----
    BLOAD(1); ALOAD(1, 0, 0);                 // p4: 12 ds_reads
    if (nl) stA(0, 1, kt2);
    LGKM8(); MIDBAR(); MFMAS(0, 0); BAR();

    ALOAD(1, 0, 1);                           // p5
    if (nl) stB(1, 0, kt3);
    MIDBAR(); MFMAS(0, 1); BAR();

    ALOAD(1, 1, 0);                           // p6
    if (nl) stB(1, 1, kt3);
    MIDBAR(); MFMAS(1, 0); BAR();

    ALOAD(1, 1, 1);                           // p7
    if (nl) stA(1, 0, kt3);
    MIDBAR(); MFMAS(1, 1);
    if (nl) { VM6(); }                        // W0: buf0 content landed
    BAR();
  }

  // Epilogue: C/D layout col = lane&15, row = (lane>>4)*4 + reg.
  float bv[4];
#pragma unroll
  for (int nr = 0; nr < 4; ++nr)
    bv[nr] = bias[(ln0 + wn * 64 + nr * 16 + fr)];
#pragma unroll
  for (int mr = 0; mr < 8; ++mr) {
    const int r0 = m0 + wm * 128 + mr * 16 + fq * 4;
#pragma unroll
    for (int nr = 0; nr < 4; ++nr) {
      const int cg = n0 + wn * 64 + nr * 16 + fr;
      f32x4 v = acc[mr][nr];
#pragma unroll
      for (int r = 0; r < 4; ++r)
        out[(size_t)(r0 + r) * NTOT + cg] = v[r] + bv[nr];
    }
  }
}

// ---------------------------------------------------------------------------
extern "C" void kernel_launch(void* const* d_in, const int* in_sizes, int n_in,
                              void* d_out, int out_size, void* d_ws,
                              size_t ws_size, hipStream_t stream) {
  const float* x     = (const float*)d_in[0];
  const float* gamma = (const float*)d_in[1];
  const float* beta  = (const float*)d_in[2];
  const float* qw    = (const float*)d_in[3];
  const float* qb    = (const float*)d_in[4];
  const float* kw    = (const float*)d_in[5];
  const float* kbia  = (const float*)d_in[6];
  const float* vw    = (const float*)d_in[7];
  const float* vb    = (const float*)d_in[8];
  float* out = (float*)d_out;

  // Workspace: [0, 32M) normed fp16 [8192][2048]; [32M, 56M) W fp16 [3][2048][2048]
  char* ws = (char*)d_ws;
  _Float16* Ahp = (_Float16*)(ws);
  _Float16* Whp = (_Float16*)(ws + (size_t)MTOT * HD * 2);

  (void)hipFuncSetAttribute((const void*)qkv_gemm_kernel,
                            hipFuncAttributeMaxDynamicSharedMemorySize, 131072);

  ln_f16_kernel<<<MTOT, 256, 0, stream>>>(x, gamma, beta, Ahp);
  w_f16_kernel<<<dim3(1024, 3), 256, 0, stream>>>(qw, kw, vw, Whp);
  qkv_gemm_kernel<<<dim3(NTOT / 256, MTOT / 256), 512, 131072, stream>>>(
      Ahp, Whp, qb, kbia, vb, out);
}